// Round 6
// baseline (297.202 us; speedup 1.0000x reference)
//
#include <hip/hip_runtime.h>
#include <hip/hip_bf16.h>

typedef unsigned short u16;

#define BDIM 8
#define LDIM 8192
#define KDIM 256      // C
#define DDIM 256      // D
#define MTOT 65536    // B*L
#define NDIM 1536     // 6*D
#define TCH  32       // scan chunk length
#define NCH  256      // chunks per sequence

// Physical column layout of G (per m-row), dir f in {0,1}, base = f*768:
//   [base + 2d + 0] = h-gate col d   [base + 2d + 1] = z-gate col d  (d<256)
//   [base + 512 + d] = s-gate col d

typedef float floatx4 __attribute__((ext_vector_type(4)));
typedef short bf16x8 __attribute__((ext_vector_type(8)));

__device__ __forceinline__ u16 f2bf(float f) {
  union { __hip_bfloat16 h; u16 u; } c;
  c.h = __float2bfloat16(f);
  return c.u;
}
__device__ __forceinline__ float bf2f(u16 u) {
  union { unsigned int i; float f; } c;
  c.i = ((unsigned int)u) << 16;
  return c.f;
}
__device__ __forceinline__ float sigmoidf_fast(float x) {
  return __builtin_amdgcn_rcpf(1.0f + __expf(-x));
}
__device__ __forceinline__ void gll16(const u16* g, u16* l) {
  __builtin_amdgcn_global_load_lds((const __attribute__((address_space(1))) void*)g,
                                   (__attribute__((address_space(3))) void*)l, 16, 0, 0);
}

// ---------------------------------------------------------------------------
// Prep: WcatT[n][k] = W(n)[k][d(n)] bf16 with the interleaved physical layout.
// ---------------------------------------------------------------------------
__global__ void prep_weights(const float* __restrict__ Wh1, const float* __restrict__ Wz1,
                             const float* __restrict__ Ws1, const float* __restrict__ Wh_1,
                             const float* __restrict__ Wz_1, const float* __restrict__ Ws_1,
                             const float* __restrict__ bh1, const float* __restrict__ bz1,
                             const float* __restrict__ bs1, const float* __restrict__ bh_1,
                             const float* __restrict__ bz_1, const float* __restrict__ bs_1,
                             u16* __restrict__ WcatT, float* __restrict__ bcat) {
  const int n = blockIdx.x;       // physical col 0..1535
  const int k = threadIdx.x;      // 0..255
  const int dir = n / 768, r = n % 768;
  int d; const float* W; const float* bb;
  if (r < 512) {
    d = r >> 1;
    if (r & 1) { W = dir ? Wz_1 : Wz1; bb = dir ? bz_1 : bz1; }
    else       { W = dir ? Wh_1 : Wh1; bb = dir ? bh_1 : bh1; }
  } else {
    d = r - 512;
    W = dir ? Ws_1 : Ws1; bb = dir ? bs_1 : bs1;
  }
  WcatT[(size_t)n * KDIM + k] = f2bf(W[k * DDIM + d]);
  if (k == 0) bcat[n] = bb[d];
}

// ---------------------------------------------------------------------------
// Convert xs fp32 -> bf16
// ---------------------------------------------------------------------------
__global__ void convert_xs(const float* __restrict__ xs, u16* __restrict__ Abf) {
  size_t i = ((size_t)blockIdx.x * 256 + threadIdx.x) * 8;
  const float4* s = (const float4*)(xs + i);
  float4 f0 = s[0], f1 = s[1];
  union { u16 u[8]; uint4 v; } t;
  t.u[0] = f2bf(f0.x); t.u[1] = f2bf(f0.y); t.u[2] = f2bf(f0.z); t.u[3] = f2bf(f0.w);
  t.u[4] = f2bf(f1.x); t.u[5] = f2bf(f1.y); t.u[6] = f2bf(f1.z); t.u[7] = f2bf(f1.w);
  *(uint4*)(Abf + i) = t.v;
}

// ---------------------------------------------------------------------------
// GEMM: 128x128 tile, BK=64, global_load_lds staging, XCD-swizzled grid,
// XOR-swizzled LDS (conflict-free, verified R5: SQ_LDS_BANK_CONFLICT = 0).
// ---------------------------------------------------------------------------
__global__ __launch_bounds__(256) void gemm_kernel(const u16* __restrict__ Abf,
                                                   const u16* __restrict__ WcatT,
                                                   const float* __restrict__ bcat,
                                                   u16* __restrict__ G) {
  __shared__ __align__(16) u16 As[8192];   // 128 rows x 64 k
  __shared__ __align__(16) u16 Bs[8192];
  const int tid = threadIdx.x;
  const int lane = tid & 63, wave = tid >> 6;
  const int wm = wave >> 1, wn = wave & 1;
  const int q = lane >> 4, r = lane & 15;

  const int xcd = blockIdx.x & 7;
  const int li  = blockIdx.x >> 3;
  const int mt  = xcd * 64 + li / 12;
  const int nt  = li % 12;
  const int m0 = mt * 128, n0 = nt * 128;

  const u16* gA[4]; const u16* gB[4]; u16* lA[4]; u16* lB[4];
#pragma unroll
  for (int j = 0; j < 4; j++) {
    const int bi = wave * 256 + j * 64 + lane;   // LDS 16B-slot idx
    const int row = bi >> 3;
    const int kq = (bi & 7) ^ (row & 7);         // logical k-block for this slot
    gA[j] = Abf   + (size_t)(m0 + row) * KDIM + kq * 8;
    gB[j] = WcatT + (size_t)(n0 + row) * KDIM + kq * 8;
    lA[j] = As + bi * 8;
    lB[j] = Bs + bi * 8;
  }

  floatx4 acc[4][4];
  floatx4 z4 = {0.f, 0.f, 0.f, 0.f};
#pragma unroll
  for (int i = 0; i < 4; i++)
#pragma unroll
    for (int j = 0; j < 4; j++) acc[i][j] = z4;

  for (int k0 = 0; k0 < KDIM; k0 += 64) {
#pragma unroll
    for (int j = 0; j < 4; j++) { gll16(gA[j] + k0, lA[j]); gll16(gB[j] + k0, lB[j]); }
    __syncthreads();
#pragma unroll
    for (int kk = 0; kk < 2; kk++) {
      bf16x8 af[4], bv[4];
#pragma unroll
      for (int i = 0; i < 4; i++) {
        const int row = wm * 64 + i * 16 + r;
        af[i] = *(const bf16x8*)(As + (row * 8 + ((kk * 4 + q) ^ (row & 7))) * 8);
      }
#pragma unroll
      for (int j = 0; j < 4; j++) {
        const int row = wn * 64 + j * 16 + r;
        bv[j] = *(const bf16x8*)(Bs + (row * 8 + ((kk * 4 + q) ^ (row & 7))) * 8);
      }
#pragma unroll
      for (int i = 0; i < 4; i++)
#pragma unroll
        for (int j = 0; j < 4; j++)
          acc[i][j] = __builtin_amdgcn_mfma_f32_16x16x32_bf16(af[i], bv[j], acc[i][j], 0, 0, 0);
    }
    __syncthreads();
  }

  // C/D layout: col = lane&15, row = (lane>>4)*4 + reg  [m89/m91]
  float bvals[4];
#pragma unroll
  for (int j = 0; j < 4; j++) bvals[j] = bcat[n0 + wn * 64 + j * 16 + r];
#pragma unroll
  for (int i = 0; i < 4; i++) {
#pragma unroll
    for (int reg = 0; reg < 4; reg++) {
      size_t grow = (size_t)(m0 + wm * 64 + i * 16 + q * 4 + reg);
      u16* dst = G + grow * NDIM + n0 + wn * 64 + r;
#pragma unroll
      for (int j = 0; j < 4; j++)
        dst[j * 16] = f2bf(acc[i][j][reg] + bvals[j]);
    }
  }
}

// ---------------------------------------------------------------------------
// Scan phase A: per-chunk affine summary. ONE wave per unit, 4 d/lane ->
// one uint4 (1 KB/wave) load per t.
// ---------------------------------------------------------------------------
__global__ __launch_bounds__(256) void scan_phaseA(const u16* __restrict__ G,
                                                   float* __restrict__ Acc,
                                                   float* __restrict__ Bcc) {
  const int slot = threadIdx.x >> 6, lane = threadIdx.x & 63;
  const int u = blockIdx.x * 4 + slot;          // 0..4095
  const int c = u & 255, b = (u >> 8) & 7, dir = u >> 11;
  const int d0 = lane * 4;
  const u16* p0 = G + (size_t)b * LDIM * NDIM + dir * 768 + d0 * 2;
  float h[4], P[4];
#pragma unroll
  for (int e = 0; e < 4; ++e) { h[e] = 0.f; P[e] = 1.f; }
#pragma unroll 8
  for (int i = 0; i < TCH; ++i) {
    const int t = dir ? (c * TCH + (TCH - 1 - i)) : (c * TCH + i);
    uint4 hz = *(const uint4*)(p0 + (size_t)t * NDIM);
    const u16* q = (const u16*)&hz;
#pragma unroll
    for (int e = 0; e < 4; ++e) {
      float z = sigmoidf_fast(bf2f(q[2 * e + 1]));
      float a = 1.f - z;
      h[e] = fmaf(a, h[e], z * bf2f(q[2 * e]));
      P[e] *= a;
    }
  }
  float4 v;
  v.x = P[0]; v.y = P[1]; v.z = P[2]; v.w = P[3];
  *(float4*)(Acc + (size_t)u * 256 + d0) = v;
  v.x = h[0]; v.y = h[1]; v.z = h[2]; v.w = h[3];
  *(float4*)(Bcc + (size_t)u * 256 + d0) = v;
}

// ---------------------------------------------------------------------------
// Scan phase B: chain 256 chunk summaries, 8-deep load batching.
// ---------------------------------------------------------------------------
__global__ void scan_phaseB(const float* __restrict__ Acc, const float* __restrict__ Bcc,
                            const float* __restrict__ h01, const float* __restrict__ h0_1,
                            float* __restrict__ Pref) {
  const int d = threadIdx.x, b = blockIdx.x, dir = blockIdx.y;
  float h = dir ? h0_1[d] : h01[d];
  const size_t ubase = ((size_t)dir * BDIM + b) * NCH;
  if (dir == 0) {
    for (int c0 = 0; c0 < NCH; c0 += 8) {
      float a[8], bb[8];
#pragma unroll
      for (int j = 0; j < 8; ++j) {
        size_t idx = (ubase + c0 + j) * DDIM + d;
        a[j] = Acc[idx]; bb[j] = Bcc[idx];
      }
#pragma unroll
      for (int j = 0; j < 8; ++j) {
        Pref[(ubase + c0 + j) * DDIM + d] = h;
        h = fmaf(a[j], h, bb[j]);
      }
    }
  } else {
    for (int c0 = NCH - 1; c0 >= 0; c0 -= 8) {
      float a[8], bb[8];
#pragma unroll
      for (int j = 0; j < 8; ++j) {
        size_t idx = (ubase + c0 - j) * DDIM + d;
        a[j] = Acc[idx]; bb[j] = Bcc[idx];
      }
#pragma unroll
      for (int j = 0; j < 8; ++j) {
        Pref[(ubase + c0 - j) * DDIM + d] = h;
        h = fmaf(a[j], h, bb[j]);
      }
    }
  }
}

// ---------------------------------------------------------------------------
// Scan phase C: block = one (b,c) chunk, 256 thr (4 waves).
// Waves 0-1 run fwd chain, waves 2-3 run bwd chain CONCURRENTLY (2 d/lane,
// 8B hz + 4B s loads); both store products as bf16 to LDS (16 KB each).
// One barrier, then cooperative coalesced merge: out = fwd + bwd (fp32).
// ---------------------------------------------------------------------------
__global__ __launch_bounds__(256) void scan_phaseC(const u16* __restrict__ G,
                                                   const float* __restrict__ Pref,
                                                   float* __restrict__ out) {
  __shared__ u16 fbuf[TCH * 256];   // 16 KB fwd products (bf16)
  __shared__ u16 bbuf[TCH * 256];   // 16 KB bwd products
  const int c = blockIdx.x & 255, b = blockIdx.x >> 8;
  const int wave = threadIdx.x >> 6, lane = threadIdx.x & 63;
  const int dir = wave >> 1, half = wave & 1;
  const int d0 = half * 128 + lane * 2;
  const int u = dir * 2048 + b * 256 + c;
  float h0 = Pref[(size_t)u * 256 + d0];
  float h1 = Pref[(size_t)u * 256 + d0 + 1];
  const u16* ghz = G + (size_t)b * LDIM * NDIM + dir * 768 + d0 * 2;
  const u16* gs  = G + (size_t)b * LDIM * NDIM + dir * 768 + 512 + d0;
  u16* buf = dir ? bbuf : fbuf;

#pragma unroll 4
  for (int i = 0; i < TCH; ++i) {
    const int tl = dir ? (TCH - 1 - i) : i;
    const int t = c * TCH + tl;
    uint2 hz = *(const uint2*)(ghz + (size_t)t * NDIM);
    unsigned int sv = *(const unsigned int*)(gs + (size_t)t * NDIM);
    const u16* q = (const u16*)&hz;
    const u16* sq = (const u16*)&sv;
    float z0 = sigmoidf_fast(bf2f(q[1]));
    float z1 = sigmoidf_fast(bf2f(q[3]));
    h0 = fmaf(1.f - z0, h0, z0 * bf2f(q[0]));
    h1 = fmaf(1.f - z1, h1, z1 * bf2f(q[2]));
    unsigned int pk = (unsigned int)f2bf(h0 * sigmoidf_fast(bf2f(sq[0])))
                    | ((unsigned int)f2bf(h1 * sigmoidf_fast(bf2f(sq[1]))) << 16);
    *(unsigned int*)(buf + tl * 256 + d0) = pk;
  }
  __syncthreads();
  // Cooperative merge: 32 rows x 256 cols; thread handles col=tid each row.
  const int tid = threadIdx.x;
  float* obase = out + ((size_t)b * LDIM + c * TCH) * DDIM + tid;
#pragma unroll 8
  for (int rrow = 0; rrow < TCH; ++rrow) {
    float v = bf2f(fbuf[rrow * 256 + tid]) + bf2f(bbuf[rrow * 256 + tid]);
    obase[(size_t)rrow * DDIM] = v;
  }
}

extern "C" void kernel_launch(void* const* d_in, const int* in_sizes, int n_in,
                              void* d_out, int out_size, void* d_ws, size_t ws_size,
                              hipStream_t stream) {
  const float* xs   = (const float*)d_in[0];
  const float* Wh1  = (const float*)d_in[1];
  const float* bh1  = (const float*)d_in[2];
  const float* Wz1  = (const float*)d_in[3];
  const float* bz1  = (const float*)d_in[4];
  const float* Ws1  = (const float*)d_in[5];
  const float* bs1  = (const float*)d_in[6];
  const float* h01  = (const float*)d_in[7];
  const float* Wh_1 = (const float*)d_in[8];
  const float* bh_1 = (const float*)d_in[9];
  const float* Wz_1 = (const float*)d_in[10];
  const float* bz_1 = (const float*)d_in[11];
  const float* Ws_1 = (const float*)d_in[12];
  const float* bs_1 = (const float*)d_in[13];
  const float* h0_1 = (const float*)d_in[14];
  float* out = (float*)d_out;

  char* ws = (char*)d_ws;
  u16* WcatT = (u16*)ws;   ws += (size_t)NDIM * KDIM * 2;   // 0.75 MB
  float* bcat = (float*)ws; ws += (size_t)NDIM * 4;         // 6 KB
  u16* Abf = (u16*)ws;     ws += (size_t)MTOT * KDIM * 2;   // 32 MB
  u16* G = (u16*)ws;       ws += (size_t)MTOT * NDIM * 2;   // 192 MB
  // Summary arrays alias Abf (dead after gemm). 12 MB <= 32 MB.
  float* Acc  = (float*)Abf;
  float* Bcc  = Acc + (size_t)2 * BDIM * NCH * DDIM;
  float* Pref = Bcc + (size_t)2 * BDIM * NCH * DDIM;
  if ((size_t)(ws - (char*)d_ws) > ws_size) return;

  prep_weights<<<dim3(NDIM), dim3(KDIM), 0, stream>>>(
      Wh1, Wz1, Ws1, Wh_1, Wz_1, Ws_1, bh1, bz1, bs1, bh_1, bz_1, bs_1, WcatT, bcat);
  convert_xs<<<dim3(MTOT * KDIM / (256 * 8)), dim3(256), 0, stream>>>(xs, Abf);
  gemm_kernel<<<dim3(6144), dim3(256), 0, stream>>>(Abf, WcatT, bcat, G);
  scan_phaseA<<<dim3(1024), dim3(256), 0, stream>>>(G, Acc, Bcc);
  scan_phaseB<<<dim3(BDIM, 2), dim3(DDIM), 0, stream>>>(Acc, Bcc, h01, h0_1, Pref);
  scan_phaseC<<<dim3(2048), dim3(256), 0, stream>>>(G, Pref, out);
}